// Round 15
// baseline (215.918 us; speedup 1.0000x reference)
//
#include <hip/hip_runtime.h>
#include <hip/hip_bf16.h>

#define E_DIM 768
#define H_DIM 64
#define B_SZ 8
#define T_SZ 4096
#define BT (B_SZ * T_SZ)   // 32768

typedef __attribute__((ext_vector_type(8))) short short8;   // 8 bf16 (MFMA A/B frag, K=32)
typedef __attribute__((ext_vector_type(4))) float floatx4;  // MFMA C/D frag

// raw barrier: LDS visibility only — does NOT drain vmcnt (prefetch stays in flight)
#define RAWBAR() __asm__ volatile("s_waitcnt lgkmcnt(0)\n\ts_barrier" ::: "memory")

static __device__ __forceinline__ unsigned short bf1(float a) {
    __hip_bfloat16 h = __float2bfloat16(a);
    unsigned short u; __builtin_memcpy(&u, &h, 2); return u;
}
static __device__ __forceinline__ unsigned int pk2(float a, float b) {
    __hip_bfloat162 h = __float22bfloat162_rn(float2{a, b});
    unsigned int u; __builtin_memcpy(&u, &h, 4); return u;
}

// ---------------- W transpose + bf16: Wt[n][k], n = nt*64+nn ----------------
// Wq additionally scaled by log2(e) so attention softmax can use exp2 directly.
__global__ __launch_bounds__(256) void prep_w(
    const float* __restrict__ Wq, const float* __restrict__ Wk,
    const float* __restrict__ Wv, unsigned short* __restrict__ Wt)
{
    __shared__ float Ls[64][65];
    const int nt = blockIdx.x;           // 0..2
    const int kc = blockIdx.y;           // 0..11 (64-k chunk)
    const float* __restrict__ W = (nt == 0) ? Wq : (nt == 1) ? Wk : Wv;
    const float scl = (nt == 0) ? 1.44269504088896f : 1.0f;
    const int t = threadIdx.x;
    const int k0 = kc * 64;

#pragma unroll
    for (int it = 0; it < 16; ++it) {
        const int kk = (t >> 6) + it * 4;
        Ls[kk][t & 63] = W[(size_t)(k0 + kk) * H_DIM + (t & 63)];
    }
    __syncthreads();

#pragma unroll
    for (int it = 0; it < 4; ++it) {
        const int nl = (t >> 4) + it * 16;
        const int kl = (t & 15) * 4;
        unsigned int u[2];
        u[0] = pk2(Ls[kl + 0][nl] * scl, Ls[kl + 1][nl] * scl);
        u[1] = pk2(Ls[kl + 2][nl] * scl, Ls[kl + 3][nl] * scl);
        *(uint2*)(Wt + (size_t)(nt * 64 + nl) * E_DIM + k0 + kl) = *(uint2*)u;
    }
}

// ---------------- projection: W-in-registers, X double-buffered in LDS ----------------
// grid 256 (128-row m-tiles), 768 threads = 12 waves; wave w owns n-tile w (Q:0-3, K:4-7, V:8-11).
// NOTE: 96-VGPR persistent W file => 1 block/CU is the only viable occupancy.
// Do NOT add a min-waves launch_bounds clause: (768,6) capped VGPRs at ~85 and
// spilled the W file to scratch (FETCH 238 MB, 140 us — round-1 regression).
// Fitted cross-round budget: proj ~29.5 us vs ~16-20 us HBM floor — near-optimal; left alone.
__global__ __launch_bounds__(768) void proj_mfma(
    const float* __restrict__ X, const unsigned short* __restrict__ Wt,
    unsigned short* __restrict__ Qb, unsigned short* __restrict__ Kb,
    unsigned short* __restrict__ Vtb)
{
    __shared__ unsigned short Xs[2][16][776];   // 16-row X tile bf16, pad 776

    const int tid  = threadIdx.x;
    const int wave = tid >> 6, lane = tid & 63;
    const int row  = lane & 15, quad = lane >> 4;
    const int m0   = blockIdx.x * 128;

    // W prologue: 24 B-frags resident in registers (96 VGPRs)
    short8 bfr[24];
    {
        const unsigned short* wp = Wt + (size_t)(wave * 16 + row) * E_DIM + quad * 8;
#pragma unroll
        for (int ks = 0; ks < 24; ++ks) bfr[ks] = *(const short8*)(wp + ks * 32);
    }

    const int srow = tid & 15;
    const int sc   = tid >> 4;
    const float* __restrict__ xbase = X + (size_t)(m0 + srow) * E_DIM + sc * 16;

    float4 fx[4];
#define LDX(mt)                                                               \
    {                                                                         \
        const float* p = xbase + (size_t)(mt) * 16 * E_DIM;                   \
        fx[0] = *(const float4*)(p);     fx[1] = *(const float4*)(p + 4);     \
        fx[2] = *(const float4*)(p + 8); fx[3] = *(const float4*)(p + 12);    \
    }
#define STX(buf)                                                              \
    {                                                                         \
        unsigned int tmp[8];                                                  \
        tmp[0] = pk2(fx[0].x, fx[0].y); tmp[1] = pk2(fx[0].z, fx[0].w);       \
        tmp[2] = pk2(fx[1].x, fx[1].y); tmp[3] = pk2(fx[1].z, fx[1].w);       \
        tmp[4] = pk2(fx[2].x, fx[2].y); tmp[5] = pk2(fx[2].z, fx[2].w);       \
        tmp[6] = pk2(fx[3].x, fx[3].y); tmp[7] = pk2(fx[3].z, fx[3].w);       \
        *(int4*)&Xs[buf][srow][sc * 16]     = *(int4*)&tmp[0];                \
        *(int4*)&Xs[buf][srow][sc * 16 + 8] = *(int4*)&tmp[4];                \
    }

    // prologue: buf0 = tile 0; tile 1 loads in flight
    LDX(0); STX(0); LDX(1);
    RAWBAR();

    const int g  = wave >> 2;            // 0=Q, 1=K, 2=V
    const int h  = (wave & 3) * 16 + row;
    unsigned short* __restrict__ OQK = (g == 0) ? Qb : Kb;
    const int bb = m0 >> 12;

    int cur = 0;
    for (int mt = 0; mt < 8; ++mt) {
        // stage tile mt+1 into the idle buffer (safe: last reads of that buffer were
        // in window mt-1, sealed by the barrier), then issue loads for tile mt+2.
        if (mt < 7) STX(cur ^ 1);
        if (mt < 6) LDX(mt + 2);

        // 4 independent accumulator chains (MFMA dep-latency hiding at 3 waves/SIMD)
        floatx4 a0 = (floatx4)0.0f, a1 = (floatx4)0.0f;
        floatx4 a2 = (floatx4)0.0f, a3 = (floatx4)0.0f;
#pragma unroll
        for (int ks = 0; ks < 6; ++ks) {
            const short8 f0 = *(const short8*)&Xs[cur][row][(ks * 4 + 0) * 32 + quad * 8];
            const short8 f1 = *(const short8*)&Xs[cur][row][(ks * 4 + 1) * 32 + quad * 8];
            const short8 f2 = *(const short8*)&Xs[cur][row][(ks * 4 + 2) * 32 + quad * 8];
            const short8 f3 = *(const short8*)&Xs[cur][row][(ks * 4 + 3) * 32 + quad * 8];
            a0 = __builtin_amdgcn_mfma_f32_16x16x32_bf16(f0, bfr[ks * 4 + 0], a0, 0, 0, 0);
            a1 = __builtin_amdgcn_mfma_f32_16x16x32_bf16(f1, bfr[ks * 4 + 1], a1, 0, 0, 0);
            a2 = __builtin_amdgcn_mfma_f32_16x16x32_bf16(f2, bfr[ks * 4 + 2], a2, 0, 0, 0);
            a3 = __builtin_amdgcn_mfma_f32_16x16x32_bf16(f3, bfr[ks * 4 + 3], a3, 0, 0, 0);
        }
        floatx4 acc;
#pragma unroll
        for (int r = 0; r < 4; ++r) acc[r] = (a0[r] + a1[r]) + (a2[r] + a3[r]);

        const int mr = m0 + mt * 16 + quad * 4;
        if (g < 2) {
#pragma unroll
            for (int r = 0; r < 4; ++r)
                OQK[(size_t)(mr + r) * H_DIM + h] = bf1(acc[r]);
        } else {
            const int t0 = mr & 4095;
            unsigned int u[2];
            u[0] = pk2(acc[0], acc[1]); u[1] = pk2(acc[2], acc[3]);
            *(uint2*)(Vtb + ((size_t)bb * H_DIM + h) * T_SZ + t0) = *(uint2*)u;
        }

        RAWBAR();
        cur ^= 1;
    }
#undef LDX
#undef STX
}

// ---------------- flash attention v13: 32 q-rows/wave, K/V frags register-shared ----------------
// Rounds 13/14 proved occupancy and barrier count are NOT binding; the per-CU LDS pipe is
// the densest term. v13 halves LDS reads per unit work: each wave owns 32 q-rows (halves
// A and B); the 4 K-frag + 4 V-frag b128 reads per 32-key strip are hoisted into registers
// ONCE and feed both halves' MFMAs. Block = 4 waves = 128-row q-tile; tile count halves
// (16.6k -> 8.4k), so total LDS-read cycles and staging traffic (266 -> 135 MB) halve.
// Single KV buffer + 2 RAWBARs + 1-ahead prefetch (v10-verified schedule); permuted-K
// staging (v9-verified): key r -> row ((r>>2)&1)*16 + ((r&31)>>3)*4 + (r&3) within each
// 32-row half, so QK packs the 16x16x32 A-frag and PV runs 4x K=32 MFMA per strip/half.
// Causal mask gates on the last TWO tiles (kt >= ntot-2; per-lane predicate exact).
// Chunks <=8 tiles (m=1..8, LPT bands); no-max softmax => partials additive.
__global__ __launch_bounds__(256, 4) void attn_mfma(
    const unsigned short* __restrict__ Qb,
    const unsigned short* __restrict__ Kb,
    const unsigned short* __restrict__ Vtb,
    float* __restrict__ Opart, float* __restrict__ lpart,
    float* __restrict__ Out)
{
    // KV[0] = permuted K tile, KV[1] = V^T tile [h][key]
    __shared__ __align__(16) unsigned short KV[2][64][72];   // 18432 B

    const int lb = blockIdx.x;                 // 0..1151
    const int b  = lb & 7;                     // batch -> XCD (L2 locality)
    const int s  = lb >> 3;                    // 0..143, LPT bands (heavy chunks first)
    int qq, c, m;
    if (s < 32)       { m = 8; qq = 28 + (s >> 3);                   c = s & 7; }
    else if (s < 60)  { m = 7; const int i = s - 32;  qq = 24 + i / 7;  c = i % 7; }
    else if (s < 84)  { m = 6; const int i = s - 60;  qq = 20 + i / 6;  c = i % 6; }
    else if (s < 104) { m = 5; const int i = s - 84;  qq = 16 + i / 5;  c = i % 5; }
    else if (s < 120) { m = 4; const int i = s - 104; qq = 12 + (i >> 2); c = i & 3; }
    else if (s < 132) { m = 3; const int i = s - 120; qq = 8 + i / 3;   c = i % 3; }
    else if (s < 140) { m = 2; const int i = s - 132; qq = 4 + (i >> 1); c = i & 1; }
    else              { m = 1; qq = s - 140; c = 0; }
    const int ntot = 2 * (qq + 1);             // 64-key tiles for this 128-row q-tile
    const int k0t  = (c * ntot) / m;
    const int k1t  = ((c + 1) * ntot) / m;
    const int n    = k1t - k0t;                // 1..8
    const bool split = (m > 1);

    const int tid  = threadIdx.x;
    const int wq   = tid >> 6;                 // wave owns q-rows wq*32..wq*32+31
    const int lane = tid & 63;
    const int col  = lane & 15, quad = lane >> 4;

    const size_t base = (size_t)b * T_SZ * H_DIM;
    const int q0  = qq * 128;

    // Q fragments: half A rows q0+wq*32+col, half B rows +16
    short8 qfA0, qfA1, qfB0, qfB1;
    {
        const unsigned short* qp = Qb + base + (size_t)(q0 + wq * 32 + col) * H_DIM + quad * 8;
        qfA0 = *(const short8*)(qp);
        qfA1 = *(const short8*)(qp + 32);
        qfB0 = *(const short8*)(qp + 16 * H_DIM);
        qfB1 = *(const short8*)(qp + 16 * H_DIM + 32);
    }

    floatx4 oA[4], oB[4];
#pragma unroll
    for (int i = 0; i < 4; ++i) { oA[i] = (floatx4)0.0f; oB[i] = (floatx4)0.0f; }
    float lpA = 0.0f, lpB = 0.0f;

    // cooperative staging: 32B of K + 32B of V^T per thread per tile (coalesced reads).
    // K LDS row is PERMUTED (v9-verified formula).
    const int krow = tid >> 2, kcol = (tid & 3) * 16;
    const int kprow = (krow & 32) + ((krow >> 2) & 1) * 16 + ((krow & 31) >> 3) * 4 + (krow & 3);
    const unsigned short* __restrict__ Ksrc = Kb + base + (size_t)krow * H_DIM + kcol;
    const unsigned short* __restrict__ Vsrc = Vtb + ((size_t)b * H_DIM + krow) * T_SZ + kcol;

    int4 kr0, kr1, vr0, vr1;
#define LDKV(t)                                                          \
    {                                                                    \
        const unsigned short* kp = Ksrc + (size_t)(t) * 64 * H_DIM;      \
        kr0 = *(const int4*)kp; kr1 = *(const int4*)(kp + 8);            \
        const unsigned short* vp = Vsrc + (t) * 64;                      \
        vr0 = *(const int4*)vp; vr1 = *(const int4*)(vp + 8);            \
    }
#define STKV()                                                           \
    {                                                                    \
        *(int4*)&KV[0][kprow][kcol] = kr0; *(int4*)&KV[0][kprow][kcol + 8] = kr1; \
        *(int4*)&KV[1][krow][kcol] = vr0; *(int4*)&KV[1][krow][kcol + 8] = vr1; \
    }

    LDKV(k0t);
    STKV();
    if (n > 1) LDKV(k0t + 1);
    RAWBAR();

    for (int i = 0; i < n; ++i) {
        const int kt = k0t + i;
        const bool dia = (kt >= ntot - 2);     // only last two tiles can mask

        // two 32-key strips; K/V fragments loaded ONCE per strip, shared by halves A+B
#pragma unroll
        for (int j = 0; j < 2; ++j) {
            // K fragments (4 b128 reads serve 8 MFMAs)
            const unsigned short* kp0 = &KV[0][j * 32 + col][quad * 8];
            const unsigned short* kp1 = &KV[0][j * 32 + 16 + col][quad * 8];
            const short8 k0 = *(const short8*)(kp0);
            const short8 k1 = *(const short8*)(kp0 + 32);
            const short8 k2 = *(const short8*)(kp1);
            const short8 k3 = *(const short8*)(kp1 + 32);

            // QK both halves: a0[r] = S[q][key = j*32 + quad*8 + r], a1[r] = +4+r
            floatx4 aA0 = (floatx4)0.0f, aA1 = (floatx4)0.0f;
            floatx4 aB0 = (floatx4)0.0f, aB1 = (floatx4)0.0f;
            __builtin_amdgcn_s_setprio(1);
            aA0 = __builtin_amdgcn_mfma_f32_16x16x32_bf16(k0, qfA0, aA0, 0, 0, 0);
            aA1 = __builtin_amdgcn_mfma_f32_16x16x32_bf16(k2, qfA0, aA1, 0, 0, 0);
            aB0 = __builtin_amdgcn_mfma_f32_16x16x32_bf16(k0, qfB0, aB0, 0, 0, 0);
            aB1 = __builtin_amdgcn_mfma_f32_16x16x32_bf16(k2, qfB0, aB1, 0, 0, 0);
            aA0 = __builtin_amdgcn_mfma_f32_16x16x32_bf16(k1, qfA1, aA0, 0, 0, 0);
            aA1 = __builtin_amdgcn_mfma_f32_16x16x32_bf16(k3, qfA1, aA1, 0, 0, 0);
            aB0 = __builtin_amdgcn_mfma_f32_16x16x32_bf16(k1, qfB1, aB0, 0, 0, 0);
            aB1 = __builtin_amdgcn_mfma_f32_16x16x32_bf16(k3, qfB1, aB1, 0, 0, 0);
            __builtin_amdgcn_s_setprio(0);

            if (dia) {                         // causal mask (per-lane exact)
                const int qgA = q0 + wq * 32 + col;
                const int qgB = qgA + 16;
                const int kb  = kt * 64 + j * 32 + quad * 8;
#pragma unroll
                for (int r = 0; r < 4; ++r) {
                    if (kb + r > qgA)     aA0[r] = -1e30f;
                    if (kb + 4 + r > qgA) aA1[r] = -1e30f;
                    if (kb + r > qgB)     aB0[r] = -1e30f;
                    if (kb + 4 + r > qgB) aB1[r] = -1e30f;
                }
            }

            // no-max softmax both halves: p = exp2(s), packs the 16x16x32 A-frag
            const float pA0 = exp2f(aA0[0]), pA1 = exp2f(aA0[1]), pA2 = exp2f(aA0[2]), pA3 = exp2f(aA0[3]);
            const float pA4 = exp2f(aA1[0]), pA5 = exp2f(aA1[1]), pA6 = exp2f(aA1[2]), pA7 = exp2f(aA1[3]);
            lpA += ((pA0 + pA1) + (pA2 + pA3)) + ((pA4 + pA5) + (pA6 + pA7));
            unsigned int uA0, uA1, uA2, uA3;
            __asm__("v_cvt_pk_bf16_f32 %0, %1, %2" : "=v"(uA0) : "v"(pA0), "v"(pA1));
            __asm__("v_cvt_pk_bf16_f32 %0, %1, %2" : "=v"(uA1) : "v"(pA2), "v"(pA3));
            __asm__("v_cvt_pk_bf16_f32 %0, %1, %2" : "=v"(uA2) : "v"(pA4), "v"(pA5));
            __asm__("v_cvt_pk_bf16_f32 %0, %1, %2" : "=v"(uA3) : "v"(pA6), "v"(pA7));
            union { unsigned int u[4]; short8 v; } puA;
            puA.u[0] = uA0; puA.u[1] = uA1; puA.u[2] = uA2; puA.u[3] = uA3;
            const short8 paA = puA.v;

            const float pB0 = exp2f(aB0[0]), pB1 = exp2f(aB0[1]), pB2 = exp2f(aB0[2]), pB3 = exp2f(aB0[3]);
            const float pB4 = exp2f(aB1[0]), pB5 = exp2f(aB1[1]), pB6 = exp2f(aB1[2]), pB7 = exp2f(aB1[3]);
            lpB += ((pB0 + pB1) + (pB2 + pB3)) + ((pB4 + pB5) + (pB6 + pB7));
            unsigned int uB0, uB1, uB2, uB3;
            __asm__("v_cvt_pk_bf16_f32 %0, %1, %2" : "=v"(uB0) : "v"(pB0), "v"(pB1));
            __asm__("v_cvt_pk_bf16_f32 %0, %1, %2" : "=v"(uB1) : "v"(pB2), "v"(pB3));
            __asm__("v_cvt_pk_bf16_f32 %0, %1, %2" : "=v"(uB2) : "v"(pB4), "v"(pB5));
            __asm__("v_cvt_pk_bf16_f32 %0, %1, %2" : "=v"(uB3) : "v"(pB6), "v"(pB7));
            union { unsigned int u[4]; short8 v; } puB;
            puB.u[0] = uB0; puB.u[1] = uB1; puB.u[2] = uB2; puB.u[3] = uB3;
            const short8 paB = puB.v;

            // V fragments (4 b128 reads serve 8 MFMAs); PV both halves
            __builtin_amdgcn_s_setprio(1);
#pragma unroll
            for (int d = 0; d < 4; ++d) {
                const short8 vb = *(const short8*)(&KV[1][d * 16 + col][j * 32 + quad * 8]);
                oA[d] = __builtin_amdgcn_mfma_f32_16x16x32_bf16(paA, vb, oA[d], 0, 0, 0);
                oB[d] = __builtin_amdgcn_mfma_f32_16x16x32_bf16(paB, vb, oB[d], 0, 0, 0);
            }
            __builtin_amdgcn_s_setprio(0);
        }

        RAWBAR();                              // all waves done reading KV
        if (i + 1 < n) {
            STKV();                            // vmcnt wait: loads issued a full iter ago
            if (i + 2 < n) LDKV(kt + 2);
        }
        RAWBAR();
    }

    // denom: reduce across the 4 quads (same col); redistribute per-o-row in-wave
    lpA += __shfl_xor(lpA, 16); lpA += __shfl_xor(lpA, 32);
    lpB += __shfl_xor(lpB, 16); lpB += __shfl_xor(lpB, 32);
    float lrA[4], lrB[4];
#pragma unroll
    for (int r = 0; r < 4; ++r) {
        lrA[r] = __shfl(lpA, quad * 4 + r);
        lrB[r] = __shfl(lpB, quad * 4 + r);
    }

    // oA[d][r] = O[q-local = quad*4+r][h = d*16+col] for rows q0+wq*32+quad*4+r; oB: +16
    if (!split) {
        float* opA = Out + base + (size_t)(q0 + wq * 32 + quad * 4) * H_DIM;
        float* opB = opA + (size_t)16 * H_DIM;
#pragma unroll
        for (int r = 0; r < 4; ++r) {
            const float invA = 1.0f / lrA[r], invB = 1.0f / lrB[r];
#pragma unroll
            for (int d = 0; d < 4; ++d) {
                opA[(size_t)r * H_DIM + d * 16 + col] = oA[d][r] * invA;
                opB[(size_t)r * H_DIM + d * 16 + col] = oB[d][r] * invB;
            }
        }
    } else {
        const int pidx = (b * 32 + qq) * 8 + c;
        float* opA = Opart + (size_t)pidx * 8192 + (wq * 32 + quad * 4) * 64;
        float* opB = opA + 16 * 64;
#pragma unroll
        for (int r = 0; r < 4; ++r)
#pragma unroll
            for (int d = 0; d < 4; ++d) {
                opA[(size_t)r * 64 + d * 16 + col] = oA[d][r];
                opB[(size_t)r * 64 + d * 16 + col] = oB[d][r];
            }
        if (quad == 0) {
            lpart[pidx * 128 + wq * 32 + col] = lpA;
            lpart[pidx * 128 + wq * 32 + 16 + col] = lpB;
        }
    }
#undef LDKV
#undef STKV
}

// ---------------- split-K combine: 128-row q-tiles qq>=4, m in {2..8} partials ----------------
__global__ __launch_bounds__(256) void attn_combine(
    const float* __restrict__ Opart, const float* __restrict__ lpart,
    float* __restrict__ Out)
{
    const int qq  = 4 + blockIdx.x;           // 4..31
    const int b   = blockIdx.y;               // 0..7
    const int m   = (2 * qq + 9) / 8;         // ceil(2(qq+1)/8) in 2..8
    const int tid = threadIdx.x;
    const int orow = tid >> 1;                // 0..127
    const int d0   = (tid & 1) * 32;
    const int p0   = (b * 32 + qq) * 8;

    float4 a[8];
#pragma unroll
    for (int i = 0; i < 8; ++i) a[i] = float4{0.f, 0.f, 0.f, 0.f};
    float l = 0.0f;
    for (int j = 0; j < m; ++j) {
        const float* P = Opart + (size_t)(p0 + j) * 8192 + orow * 64 + d0;
#pragma unroll
        for (int i = 0; i < 8; ++i) {
            const float4 v = *(const float4*)(P + i * 4);
            a[i].x += v.x; a[i].y += v.y; a[i].z += v.z; a[i].w += v.w;
        }
        l += lpart[(p0 + j) * 128 + orow];
    }
    const float inv = 1.0f / l;
    float* op = Out + ((size_t)b * T_SZ + qq * 128 + orow) * H_DIM + d0;
#pragma unroll
    for (int i = 0; i < 8; ++i) {
        a[i].x *= inv; a[i].y *= inv; a[i].z *= inv; a[i].w *= inv;
        *(float4*)(op + i * 4) = a[i];
    }
}

extern "C" void kernel_launch(void* const* d_in, const int* in_sizes, int n_in,
                              void* d_out, int out_size, void* d_ws, size_t ws_size,
                              hipStream_t stream) {
    const float* X  = (const float*)d_in[0];
    const float* Wq = (const float*)d_in[1];
    const float* Wk = (const float*)d_in[2];
    const float* Wv = (const float*)d_in[3];

    unsigned short* Wt  = (unsigned short*)d_ws;            // 192*768 bf16
    unsigned short* Qb  = Wt + (size_t)192 * E_DIM;
    unsigned short* Kb  = Qb + (size_t)BT * H_DIM;
    unsigned short* Vtb = Kb + (size_t)BT * H_DIM;          // V transposed [b][h][t]
    float* Opart = (float*)(Vtb + (size_t)BT * H_DIM);      // [2048][128][64] f32 = 64 MB
    float* lpart = Opart + (size_t)2048 * 8192;             // [2048][128] f32

    prep_w<<<dim3(3, 12), 256, 0, stream>>>(Wq, Wk, Wv, Wt);
    proj_mfma<<<256, 768, 0, stream>>>(X, Wt, Qb, Kb, Vtb);
    attn_mfma<<<1152, 256, 0, stream>>>(Qb, Kb, Vtb, Opart, lpart, (float*)d_out);
    attn_combine<<<dim3(28, 8), 256, 0, stream>>>(Opart, lpart, (float*)d_out);
}

// Round 16
// 211.764 us; speedup vs baseline: 1.0196x; 1.0196x over previous
//
#include <hip/hip_runtime.h>
#include <hip/hip_bf16.h>

#define E_DIM 768
#define H_DIM 64
#define B_SZ 8
#define T_SZ 4096
#define BT (B_SZ * T_SZ)   // 32768

typedef __attribute__((ext_vector_type(8))) short short8;   // 8 bf16 (MFMA A/B frag, K=32)
typedef __attribute__((ext_vector_type(4))) float floatx4;  // MFMA C/D frag

// raw barrier: LDS visibility only — does NOT drain vmcnt (prefetch stays in flight)
#define RAWBAR() __asm__ volatile("s_waitcnt lgkmcnt(0)\n\ts_barrier" ::: "memory")

static __device__ __forceinline__ unsigned short bf1(float a) {
    __hip_bfloat16 h = __float2bfloat16(a);
    unsigned short u; __builtin_memcpy(&u, &h, 2); return u;
}
static __device__ __forceinline__ unsigned int pk2(float a, float b) {
    __hip_bfloat162 h = __float22bfloat162_rn(float2{a, b});
    unsigned int u; __builtin_memcpy(&u, &h, 4); return u;
}

// ---------------- W transpose + bf16: Wt[n][k], n = nt*64+nn ----------------
// Wq additionally scaled by log2(e) so attention softmax can use exp2 directly.
__global__ __launch_bounds__(256) void prep_w(
    const float* __restrict__ Wq, const float* __restrict__ Wk,
    const float* __restrict__ Wv, unsigned short* __restrict__ Wt)
{
    __shared__ float Ls[64][65];
    const int nt = blockIdx.x;           // 0..2
    const int kc = blockIdx.y;           // 0..11 (64-k chunk)
    const float* __restrict__ W = (nt == 0) ? Wq : (nt == 1) ? Wk : Wv;
    const float scl = (nt == 0) ? 1.44269504088896f : 1.0f;
    const int t = threadIdx.x;
    const int k0 = kc * 64;

#pragma unroll
    for (int it = 0; it < 16; ++it) {
        const int kk = (t >> 6) + it * 4;
        Ls[kk][t & 63] = W[(size_t)(k0 + kk) * H_DIM + (t & 63)];
    }
    __syncthreads();

#pragma unroll
    for (int it = 0; it < 4; ++it) {
        const int nl = (t >> 4) + it * 16;
        const int kl = (t & 15) * 4;
        unsigned int u[2];
        u[0] = pk2(Ls[kl + 0][nl] * scl, Ls[kl + 1][nl] * scl);
        u[1] = pk2(Ls[kl + 2][nl] * scl, Ls[kl + 3][nl] * scl);
        *(uint2*)(Wt + (size_t)(nt * 64 + nl) * E_DIM + k0 + kl) = *(uint2*)u;
    }
}

// ---------------- projection: W-in-registers, X double-buffered in LDS ----------------
// grid 256 (128-row m-tiles), 768 threads = 12 waves; wave w owns n-tile w (Q:0-3, K:4-7, V:8-11).
// NOTE: 96-VGPR persistent W file => 1 block/CU is the only viable occupancy.
// Do NOT add a min-waves launch_bounds clause: (768,6) capped VGPRs at ~85 and
// spilled the W file to scratch (FETCH 238 MB, 140 us — round-1 regression).
// Fitted cross-round budget: proj ~29.5 us vs ~16-20 us HBM floor — near-optimal; left alone.
__global__ __launch_bounds__(768) void proj_mfma(
    const float* __restrict__ X, const unsigned short* __restrict__ Wt,
    unsigned short* __restrict__ Qb, unsigned short* __restrict__ Kb,
    unsigned short* __restrict__ Vtb)
{
    __shared__ unsigned short Xs[2][16][776];   // 16-row X tile bf16, pad 776

    const int tid  = threadIdx.x;
    const int wave = tid >> 6, lane = tid & 63;
    const int row  = lane & 15, quad = lane >> 4;
    const int m0   = blockIdx.x * 128;

    // W prologue: 24 B-frags resident in registers (96 VGPRs)
    short8 bfr[24];
    {
        const unsigned short* wp = Wt + (size_t)(wave * 16 + row) * E_DIM + quad * 8;
#pragma unroll
        for (int ks = 0; ks < 24; ++ks) bfr[ks] = *(const short8*)(wp + ks * 32);
    }

    const int srow = tid & 15;
    const int sc   = tid >> 4;
    const float* __restrict__ xbase = X + (size_t)(m0 + srow) * E_DIM + sc * 16;

    float4 fx[4];
#define LDX(mt)                                                               \
    {                                                                         \
        const float* p = xbase + (size_t)(mt) * 16 * E_DIM;                   \
        fx[0] = *(const float4*)(p);     fx[1] = *(const float4*)(p + 4);     \
        fx[2] = *(const float4*)(p + 8); fx[3] = *(const float4*)(p + 12);    \
    }
#define STX(buf)                                                              \
    {                                                                         \
        unsigned int tmp[8];                                                  \
        tmp[0] = pk2(fx[0].x, fx[0].y); tmp[1] = pk2(fx[0].z, fx[0].w);       \
        tmp[2] = pk2(fx[1].x, fx[1].y); tmp[3] = pk2(fx[1].z, fx[1].w);       \
        tmp[4] = pk2(fx[2].x, fx[2].y); tmp[5] = pk2(fx[2].z, fx[2].w);       \
        tmp[6] = pk2(fx[3].x, fx[3].y); tmp[7] = pk2(fx[3].z, fx[3].w);       \
        *(int4*)&Xs[buf][srow][sc * 16]     = *(int4*)&tmp[0];                \
        *(int4*)&Xs[buf][srow][sc * 16 + 8] = *(int4*)&tmp[4];                \
    }

    // prologue: buf0 = tile 0; tile 1 loads in flight
    LDX(0); STX(0); LDX(1);
    RAWBAR();

    const int g  = wave >> 2;            // 0=Q, 1=K, 2=V
    const int h  = (wave & 3) * 16 + row;
    unsigned short* __restrict__ OQK = (g == 0) ? Qb : Kb;
    const int bb = m0 >> 12;

    int cur = 0;
    for (int mt = 0; mt < 8; ++mt) {
        // stage tile mt+1 into the idle buffer (safe: last reads of that buffer were
        // in window mt-1, sealed by the barrier), then issue loads for tile mt+2.
        if (mt < 7) STX(cur ^ 1);
        if (mt < 6) LDX(mt + 2);

        // 4 independent accumulator chains (MFMA dep-latency hiding at 3 waves/SIMD)
        floatx4 a0 = (floatx4)0.0f, a1 = (floatx4)0.0f;
        floatx4 a2 = (floatx4)0.0f, a3 = (floatx4)0.0f;
#pragma unroll
        for (int ks = 0; ks < 6; ++ks) {
            const short8 f0 = *(const short8*)&Xs[cur][row][(ks * 4 + 0) * 32 + quad * 8];
            const short8 f1 = *(const short8*)&Xs[cur][row][(ks * 4 + 1) * 32 + quad * 8];
            const short8 f2 = *(const short8*)&Xs[cur][row][(ks * 4 + 2) * 32 + quad * 8];
            const short8 f3 = *(const short8*)&Xs[cur][row][(ks * 4 + 3) * 32 + quad * 8];
            a0 = __builtin_amdgcn_mfma_f32_16x16x32_bf16(f0, bfr[ks * 4 + 0], a0, 0, 0, 0);
            a1 = __builtin_amdgcn_mfma_f32_16x16x32_bf16(f1, bfr[ks * 4 + 1], a1, 0, 0, 0);
            a2 = __builtin_amdgcn_mfma_f32_16x16x32_bf16(f2, bfr[ks * 4 + 2], a2, 0, 0, 0);
            a3 = __builtin_amdgcn_mfma_f32_16x16x32_bf16(f3, bfr[ks * 4 + 3], a3, 0, 0, 0);
        }
        floatx4 acc;
#pragma unroll
        for (int r = 0; r < 4; ++r) acc[r] = (a0[r] + a1[r]) + (a2[r] + a3[r]);

        const int mr = m0 + mt * 16 + quad * 4;
        if (g < 2) {
#pragma unroll
            for (int r = 0; r < 4; ++r)
                OQK[(size_t)(mr + r) * H_DIM + h] = bf1(acc[r]);
        } else {
            const int t0 = mr & 4095;
            unsigned int u[2];
            u[0] = pk2(acc[0], acc[1]); u[1] = pk2(acc[2], acc[3]);
            *(uint2*)(Vtb + ((size_t)bb * H_DIM + h) * T_SZ + t0) = *(uint2*)u;
        }

        RAWBAR();
        cur ^= 1;
    }
#undef LDX
#undef STX
}

// ---------------- flash attention v10: 64-row q-tiles, full-key waves, ILP2 ----------------
// SESSION-BEST configuration (round 11: 212.1 us total). Each wave owns 16 q-rows and
// processes ALL 64 keys of each tile as two independent 32-key strip chains (QK/exp2 of
// strip 1 overlaps PV of strip 0). Single 18.4 KB KV buffer, 2 raw barriers/iter,
// 1-ahead register prefetch. K rows staged PERMUTED (v9-verified): within each 32-row
// half, key r -> row ((r>>2)&1)*16 + ((r&31)>>3)*4 + (r&3), so QK output packs the
// 16x16x32 A-frag and PV runs as 4x K=32 MFMA per strip with b128 V^T reads.
// Chunks of <=12 tiles (m=1..6), no-max softmax => partials additive.
// Explored and rejected neighbors (all neutral or worse): (256,6) occupancy (r13 +0),
// dbuf 1-barrier (r14 +0), K/V-frag reg-sharing 32q/wave (r15 -3), global fragment-major
// zero-LDS (r12 -35), 2-wave blocks (r9 -5). This structure is the measured fixed point.
__global__ __launch_bounds__(256, 5) void attn_mfma(
    const unsigned short* __restrict__ Qb,
    const unsigned short* __restrict__ Kb,
    const unsigned short* __restrict__ Vtb,
    float* __restrict__ Opart, float* __restrict__ lpart,
    float* __restrict__ Out)
{
    // KV[0] = permuted K tile, KV[1] = V^T tile [h][key]
    __shared__ __align__(16) unsigned short KV[2][64][72];   // 18432 B

    const int lb = blockIdx.x;
    const int b  = lb & 7;                     // batch -> XCD (L2 locality)
    const int s  = lb >> 3;                    // 0..203, LPT-ordered (heavy chunks first)
    int qq, c, m;
    if (s < 24)       { m = 6; qq = 60 + s / 6;                        c = s % 6; }
    else if (s < 84)  { m = 5; const int i = s - 24;  qq = 48 + i / 5;    c = i % 5; }
    else if (s < 132) { m = 4; const int i = s - 84;  qq = 36 + (i >> 2); c = i & 3; }
    else if (s < 168) { m = 3; const int i = s - 132; qq = 24 + i / 3;    c = i % 3; }
    else if (s < 192) { m = 2; const int i = s - 168; qq = 12 + (i >> 1); c = i & 1; }
    else              { m = 1; qq = s - 192; c = 0; }
    const int ntot = qq + 1;                   // 64-key tiles for this 64-row q-tile
    const int k0t  = (c * ntot) / m;
    const int k1t  = ((c + 1) * ntot) / m;
    const int ktd  = ntot - 1;                 // diagonal tile (global index)
    const int n    = k1t - k0t;                // 1..12
    const bool split = (m > 1);

    const int tid  = threadIdx.x;
    const int wq   = tid >> 6;                 // wave owns q-rows wq*16..wq*16+15
    const int lane = tid & 63;
    const int col  = lane & 15, quad = lane >> 4;

    const size_t base = (size_t)b * T_SZ * H_DIM;
    const int q0  = qq * 64;

    // Q fragments: lane holds Q[q=col][h=quad*8..], the 16x16x32 B-operand
    short8 qf0, qf1;
    {
        const unsigned short* qp = Qb + base + (size_t)(q0 + wq * 16 + col) * H_DIM + quad * 8;
        qf0 = *(const short8*)(qp);
        qf1 = *(const short8*)(qp + 32);
    }

    floatx4 o[4];
#pragma unroll
    for (int i = 0; i < 4; ++i) o[i] = (floatx4)0.0f;
    float lp = 0.0f;                           // per-lane denom partial (q=col)

    // cooperative staging: 32B of K + 32B of V^T per thread per tile (coalesced reads).
    // K LDS row is PERMUTED (v9-verified formula).
    const int krow = tid >> 2, kcol = (tid & 3) * 16;
    const int kprow = (krow & 32) + ((krow >> 2) & 1) * 16 + ((krow & 31) >> 3) * 4 + (krow & 3);
    const unsigned short* __restrict__ Ksrc = Kb + base + (size_t)krow * H_DIM + kcol;
    const unsigned short* __restrict__ Vsrc = Vtb + ((size_t)b * H_DIM + krow) * T_SZ + kcol;

    int4 kr0, kr1, vr0, vr1;
#define LDKV(t)                                                          \
    {                                                                    \
        const unsigned short* kp = Ksrc + (size_t)(t) * 64 * H_DIM;      \
        kr0 = *(const int4*)kp; kr1 = *(const int4*)(kp + 8);            \
        const unsigned short* vp = Vsrc + (t) * 64;                      \
        vr0 = *(const int4*)vp; vr1 = *(const int4*)(vp + 8);            \
    }
#define STKV()                                                           \
    {                                                                    \
        *(int4*)&KV[0][kprow][kcol] = kr0; *(int4*)&KV[0][kprow][kcol + 8] = kr1; \
        *(int4*)&KV[1][krow][kcol] = vr0; *(int4*)&KV[1][krow][kcol + 8] = vr1; \
    }

    LDKV(k0t);
    STKV();
    if (n > 1) LDKV(k0t + 1);
    RAWBAR();

    for (int i = 0; i < n; ++i) {
        const int kt = k0t + i;

        // two independent 32-key strip chains; compiler interleaves them
#pragma unroll
        for (int j = 0; j < 2; ++j) {
            // S^T = K Q^T, A = permuted K rows: a0[r] = S[q=col][key = j*32 + quad*8 + r],
            // a1[r] = ... + 4 + r
            floatx4 a0 = (floatx4)0.0f, a1 = (floatx4)0.0f;
            __builtin_amdgcn_s_setprio(1);
            {
                const unsigned short* kp0 = &KV[0][j * 32 + col][quad * 8];
                const unsigned short* kp1 = &KV[0][j * 32 + 16 + col][quad * 8];
                a0 = __builtin_amdgcn_mfma_f32_16x16x32_bf16(*(const short8*)(kp0),      qf0, a0, 0, 0, 0);
                a1 = __builtin_amdgcn_mfma_f32_16x16x32_bf16(*(const short8*)(kp1),      qf0, a1, 0, 0, 0);
                a0 = __builtin_amdgcn_mfma_f32_16x16x32_bf16(*(const short8*)(kp0 + 32), qf1, a0, 0, 0, 0);
                a1 = __builtin_amdgcn_mfma_f32_16x16x32_bf16(*(const short8*)(kp1 + 32), qf1, a1, 0, 0, 0);
            }
            __builtin_amdgcn_s_setprio(0);

            if (kt == ktd) {                   // causal mask on diagonal tile
                const int qg = q0 + wq * 16 + col;
                const int kb = kt * 64 + j * 32 + quad * 8;
#pragma unroll
                for (int r = 0; r < 4; ++r) {
                    if (kb + r > qg)     a0[r] = -1e30f;
                    if (kb + 4 + r > qg) a1[r] = -1e30f;
                }
            }

            // no-max softmax: p = exp2(s); packs straight into the 16x16x32 A-frag
            const float p0 = exp2f(a0[0]), p1 = exp2f(a0[1]), p2 = exp2f(a0[2]), p3 = exp2f(a0[3]);
            const float p4 = exp2f(a1[0]), p5 = exp2f(a1[1]), p6 = exp2f(a1[2]), p7 = exp2f(a1[3]);
            lp += ((p0 + p1) + (p2 + p3)) + ((p4 + p5) + (p6 + p7));
            unsigned int u0, u1, u2, u3;
            __asm__("v_cvt_pk_bf16_f32 %0, %1, %2" : "=v"(u0) : "v"(p0), "v"(p1));
            __asm__("v_cvt_pk_bf16_f32 %0, %1, %2" : "=v"(u1) : "v"(p2), "v"(p3));
            __asm__("v_cvt_pk_bf16_f32 %0, %1, %2" : "=v"(u2) : "v"(p4), "v"(p5));
            __asm__("v_cvt_pk_bf16_f32 %0, %1, %2" : "=v"(u3) : "v"(p6), "v"(p7));
            union { unsigned int u[4]; short8 v; } pu;
            pu.u[0] = u0; pu.u[1] = u1; pu.u[2] = u2; pu.u[3] = u3;
            const short8 pa = pu.v;

            // O += P V over this strip: 4x K=32 MFMA, B = V^T b128 slices
            __builtin_amdgcn_s_setprio(1);
#pragma unroll
            for (int d = 0; d < 4; ++d) {
                const short8 vb = *(const short8*)(&KV[1][d * 16 + col][j * 32 + quad * 8]);
                o[d] = __builtin_amdgcn_mfma_f32_16x16x32_bf16(pa, vb, o[d], 0, 0, 0);
            }
            __builtin_amdgcn_s_setprio(0);
        }

        RAWBAR();                              // all waves done reading KV
        if (i + 1 < n) {
            STKV();                            // vmcnt wait: loads issued a full iter ago
            if (i + 2 < n) LDKV(kt + 2);
        }
        RAWBAR();
    }

    // denom: reduce lp across the 4 quads (same col); fetch per-o-row values in-wave
    lp += __shfl_xor(lp, 16);
    lp += __shfl_xor(lp, 32);
    float lr[4];
#pragma unroll
    for (int r = 0; r < 4; ++r) lr[r] = __shfl(lp, quad * 4 + r);

    // o[d][r] = O[q-local = quad*4 + r][h = d*16 + col] for q-rows wq*16 + quad*4 + r
    if (!split) {
        float* op = Out + base + (size_t)(q0 + wq * 16 + quad * 4) * H_DIM;
#pragma unroll
        for (int r = 0; r < 4; ++r) {
            const float inv = 1.0f / lr[r];
#pragma unroll
            for (int d = 0; d < 4; ++d)
                op[(size_t)r * H_DIM + d * 16 + col] = o[d][r] * inv;
        }
    } else {
        const int pidx = (b * 64 + qq) * 6 + c;
        float* op = Opart + ((size_t)pidx * 64 + wq * 16 + quad * 4) * 64;
#pragma unroll
        for (int r = 0; r < 4; ++r)
#pragma unroll
            for (int d = 0; d < 4; ++d)
                op[(size_t)r * 64 + d * 16 + col] = o[d][r];
        if (quad == 0) lpart[pidx * 64 + wq * 16 + col] = lp;
    }
#undef LDKV
#undef STKV
}

// ---------------- split-K combine: 64-row q-tiles qq>=12, m in {2..6} partials ----------------
__global__ __launch_bounds__(256) void attn_combine(
    const float* __restrict__ Opart, const float* __restrict__ lpart,
    float* __restrict__ Out)
{
    const int qq  = 12 + blockIdx.x;          // 12..63
    const int b   = blockIdx.y;               // 0..7
    const int m   = (qq + 12) / 12;           // ceil((qq+1)/12) in 2..6
    const int tid = threadIdx.x;
    const int orow = tid >> 2;                // 0..63
    const int d0   = (tid & 3) * 16;
    const int p0   = (b * 64 + qq) * 6;

    float4 a0 = {0.f,0.f,0.f,0.f}, a1 = {0.f,0.f,0.f,0.f};
    float4 a2 = {0.f,0.f,0.f,0.f}, a3 = {0.f,0.f,0.f,0.f};
    float l = 0.0f;
    for (int j = 0; j < m; ++j) {
        const float* P = Opart + ((size_t)(p0 + j) * 64 + orow) * 64 + d0;
        const float4 b0 = *(const float4*)(P);
        const float4 b1 = *(const float4*)(P + 4);
        const float4 b2 = *(const float4*)(P + 8);
        const float4 b3 = *(const float4*)(P + 12);
        a0.x += b0.x; a0.y += b0.y; a0.z += b0.z; a0.w += b0.w;
        a1.x += b1.x; a1.y += b1.y; a1.z += b1.z; a1.w += b1.w;
        a2.x += b2.x; a2.y += b2.y; a2.z += b2.z; a2.w += b2.w;
        a3.x += b3.x; a3.y += b3.y; a3.z += b3.z; a3.w += b3.w;
        l += lpart[(p0 + j) * 64 + orow];
    }
    const float inv = 1.0f / l;
    a0.x *= inv; a0.y *= inv; a0.z *= inv; a0.w *= inv;
    a1.x *= inv; a1.y *= inv; a1.z *= inv; a1.w *= inv;
    a2.x *= inv; a2.y *= inv; a2.z *= inv; a2.w *= inv;
    a3.x *= inv; a3.y *= inv; a3.z *= inv; a3.w *= inv;

    float* op = Out + ((size_t)b * T_SZ + qq * 64 + orow) * H_DIM + d0;
    *(float4*)(op)      = a0;
    *(float4*)(op + 4)  = a1;
    *(float4*)(op + 8)  = a2;
    *(float4*)(op + 12) = a3;
}

extern "C" void kernel_launch(void* const* d_in, const int* in_sizes, int n_in,
                              void* d_out, int out_size, void* d_ws, size_t ws_size,
                              hipStream_t stream) {
    const float* X  = (const float*)d_in[0];
    const float* Wq = (const float*)d_in[1];
    const float* Wk = (const float*)d_in[2];
    const float* Wv = (const float*)d_in[3];

    unsigned short* Wt  = (unsigned short*)d_ws;            // 192*768 bf16
    unsigned short* Qb  = Wt + (size_t)192 * E_DIM;
    unsigned short* Kb  = Qb + (size_t)BT * H_DIM;
    unsigned short* Vtb = Kb + (size_t)BT * H_DIM;          // V transposed [b][h][t]
    float* Opart = (float*)(Vtb + (size_t)BT * H_DIM);      // [3072][64][64] f32 = 50.3 MB
    float* lpart = Opart + (size_t)3072 * 64 * 64;          // [3072][64] f32

    prep_w<<<dim3(3, 12), 256, 0, stream>>>(Wq, Wk, Wv, Wt);
    proj_mfma<<<256, 768, 0, stream>>>(X, Wt, Qb, Kb, Vtb);
    attn_mfma<<<1632, 256, 0, stream>>>(Qb, Kb, Vtb, Opart, lpart, (float*)d_out);
    attn_combine<<<dim3(52, 8), 256, 0, stream>>>(Opart, lpart, (float*)d_out);
}